// Round 17
// baseline (17091.975 us; speedup 1.0000x reference)
//
#include <hip/hip_runtime.h>
#include <hip/hip_bf16.h>

// FF_27650999451977: 2-layer gated RNN (MGU), SEQ=512, B=64, H=IN=512, FP32 I/O.
// Round-17: BATCH-ROW partitioning -> communication-free recurrence.
// 4-stage pipeline: X0 (x@Wx, ringA) -> R0 (h0 recurrence, ringB) ->
// X1 (h0@Wx1, ringC) -> R1 (h1 recurrence, out). R-stages keep h entirely
// CU-local (registers + LDS); weights streamed from L2 each step; the only
// cross-WG edges are pipelined rings with 8-step slack (stamped u32 words,
// bounded polls). Critical cycle = per-CU MFMA throughput, no LLC RT.

#define SEQn 512
#define Bn   64
#define Hn   512
#define RING 8
#define BH   32768      // 64*512 dwords
#define NBH  65536      // 64*1024 dwords (ringA/C slot)

#define F_R0(g) ((g) << 4)          // ringA consumption progress (R0)
#define F_X1(i) ((8 + (i)) << 4)    // ringB consumption progress (X1), i = g*2+uh
#define F_R1(g) ((24 + (g)) << 4)   // ringC consumption progress (R1)
#define SPIN 16384u

typedef __bf16 bf16x8 __attribute__((ext_vector_type(8)));
typedef float  f32x4  __attribute__((ext_vector_type(4)));
typedef unsigned u32;
typedef unsigned short u16;

__device__ __forceinline__ u32 cload(const u32* p) {
    return __hip_atomic_load(p, __ATOMIC_RELAXED, __HIP_MEMORY_SCOPE_AGENT);
}
__device__ __forceinline__ void cstore(u32* p, u32 v) {
    __hip_atomic_store(p, v, __ATOMIC_RELAXED, __HIP_MEMORY_SCOPE_AGENT);
}
__device__ __forceinline__ u16 f2bf(float f) {
    u32 u = __float_as_uint(f);
    u += 0x7FFFu + ((u >> 16) & 1u);
    return (u16)(u >> 16);
}
__device__ __forceinline__ float bf2f(u16 v) {
    union { u32 u; float f; } x; x.u = ((u32)v) << 16; return x.f;
}

__global__ void __launch_bounds__(256, 1)
rnn_pipeline(const float* __restrict__ x,
             const float* __restrict__ Wjx, const float* __restrict__ bjx,
             const float* __restrict__ Wjh, const float* __restrict__ bjh,
             const float* __restrict__ Wkx, const float* __restrict__ bkx,
             const float* __restrict__ Wkh, const float* __restrict__ bkh,
             float* __restrict__ out,    // [SEQ][B][H] + [2][B][H] fp32
             u32* __restrict__ ringA,    // [8][64][1024] stamped preJK0
             u32* __restrict__ ringB,    // [8][64][512]  stamped h0
             u32* __restrict__ ringC,    // [8][64][1024] stamped preJK1
             u32* __restrict__ flags)
{
    const int tid  = threadIdx.x;
    const int wave = tid >> 6;
    const int lane = tid & 63;
    const int wg   = blockIdx.x;
    const int r15  = lane & 15;
    const int q    = lane >> 4;

    __shared__ char aT[16384];      // A-tile bf16 [16][512], XOR-swizzled
    __shared__ u16  pjk[16384];     // R: preJK bf16 [16][1024], linear

    bf16x8 af[16];                  // A-fragments (full K=512), per wave
    auto load_afrags = [&]() {
        const int rb = r15 << 10, sz = (r15 & 7) << 4;
#pragma unroll
        for (int kt = 0; kt < 16; ++kt) {
            const int k = (kt << 5) + (q << 3);
            af[kt] = *(const bf16x8*)(aT + ((rb + (k << 1)) ^ sz));
        }
    };
    // one 16x16 N-tile over K=512: stream fp32 weights, cvt, 16 MFMA
    auto tile = [&](f32x4& acc, const float* W, int ub) {
#pragma unroll
        for (int kt = 0; kt < 16; ++kt) {
            const float* p = W + (size_t)(ub + r15) * Hn + (kt << 5) + (q << 3);
            const f32x4 f0 = *(const f32x4*)p;
            const f32x4 f1 = *(const f32x4*)(p + 4);
            bf16x8 bf;
            bf[0] = (__bf16)f0[0]; bf[1] = (__bf16)f0[1];
            bf[2] = (__bf16)f0[2]; bf[3] = (__bf16)f0[3];
            bf[4] = (__bf16)f1[0]; bf[5] = (__bf16)f1[1];
            bf[6] = (__bf16)f1[2]; bf[7] = (__bf16)f1[3];
            acc = __builtin_amdgcn_mfma_f32_16x16x32_bf16(af[kt], bf, acc, 0, 0, 0);
        }
    };

    if (wg < 8) {
        // ====================== R role (recurrent, critical) ======================
        const int l = wg >> 2, g = wg & 3;
        const float* Wj = Wjh + (size_t)l * Hn * Hn;
        const float* Wk = Wkh + (size_t)l * Hn * Hn;
        u32* ringIn = (l == 0) ? ringA : ringC;
        u32* fIn    = flags + ((l == 0) ? F_R0(g) : F_R1(g));
        const int wub = wave << 7;           // 128 units per wave

        for (int i = tid; i < 8192; i += 256) ((u16*)aT)[i] = 0;   // h(-1) = 0
        float hreg[8][4] = {};
        __syncthreads();

        // prologue: stage ringIn[0] (stamp 1)
        {
            const u32* src = ringIn + ((size_t)g << 14);
            u32 v[64]; u32 it = 0;
            while (true) {
                bool ok = true;
#pragma unroll
                for (int b = 0; b < 64; ++b) v[b] = cload(src + (b << 8) + tid);
#pragma unroll
                for (int b = 0; b < 64; ++b) ok &= ((v[b] & 0xFFFFu) == 1u);
                if (__all(ok)) break;
                if (++it > SPIN) break;
                __builtin_amdgcn_s_sleep(1);
            }
#pragma unroll
            for (int b = 0; b < 64; ++b) pjk[(b << 8) + tid] = (u16)(v[b] >> 16);
            if (tid == 0) cstore(fIn, 1u);
        }
        __syncthreads();

        for (int t = 0; t < SEQn; ++t) {
            // issue prefetch of ringIn[t+1] (hides under MFMA phase)
            u32 pf[64];
            const u32* psrc = ringIn + (size_t)((t + 1) & 7) * NBH + ((size_t)g << 14);
            if (t + 1 < SEQn) {
#pragma unroll
                for (int b = 0; b < 64; ++b) pf[b] = cload(psrc + (b << 8) + tid);
            }
            // R0: prefetch back-pressure flags (checked later, hidden)
            u32 fa = 0xFFFFu, fb = 0xFFFFu;
            if (l == 0 && t >= RING) {
                fa = cload(flags + F_X1(g << 1));
                fb = cload(flags + F_X1((g << 1) | 1));
            }
            load_afrags();
            __syncthreads();   // A: hT reads done (phase 2 overwrites it)

            if (l == 0 && t >= RING) {
                const int bw = t - 7;
                if ((int)fa < bw || (int)fb < bw) {
                    u32 it = 0;
                    while (true) {
                        int f0 = (int)cload(flags + F_X1(g << 1));
                        int f1 = (int)cload(flags + F_X1((g << 1) | 1));
                        if (f0 >= bw && f1 >= bw) break;
                        if (++it > SPIN) break;
                        __builtin_amdgcn_s_sleep(1);
                    }
                }
            }

#pragma unroll
            for (int blk = 0; blk < 8; ++blk) {
                const int uj = wub + (blk << 4);
                f32x4 ja, ka;
#pragma unroll
                for (int i = 0; i < 4; ++i) {
                    const int row = (q << 2) + i;
                    ja[i] = bf2f(pjk[(row << 10) + uj + r15]);
                    ka[i] = bf2f(pjk[(row << 10) + 512 + uj + r15]);
                }
                tile(ja, Wj, uj);
                tile(ka, Wk, uj);
#pragma unroll
                for (int i = 0; i < 4; ++i) {
                    const float jj = 1.f / (1.f + __expf(-ja[i]));
                    const float kk = 1.f / (1.f + __expf(-ka[i]));
                    const float h  = hreg[blk][i];
                    const float hn = jj * (1.f - h) + (1.f - kk) * h;
                    hreg[blk][i] = hn;
                    const int row = (q << 2) + i, unit = uj + r15;
                    const u16 hb = f2bf(hn);
                    *(u16*)(aT + ((((row << 9) + unit) << 1) ^ ((row & 7) << 4))) = hb;
                    if (l == 0)
                        cstore(ringB + (size_t)(t & 7) * BH + (size_t)(((g << 4) + row) << 9) + unit,
                               ((u32)hb << 16) | (u32)(t + 1));
                    else
                        out[(size_t)t * BH + (size_t)(((g << 4) + row) << 9) + unit] = hn;
                    if (t == SEQn - 1)
                        out[(size_t)SEQn * BH + (size_t)l * BH +
                            (size_t)(((g << 4) + row) << 9) + unit] = hn;
                }
            }
            __syncthreads();   // B: pjk reads + hT writes done

            if (t + 1 < SEQn) {
                const u32 want = (u32)(t + 2);
                bool ok = true;
#pragma unroll
                for (int b = 0; b < 64; ++b) ok &= ((pf[b] & 0xFFFFu) == want);
                u32 it = 0;
                while (!__all(ok)) {
#pragma unroll
                    for (int b = 0; b < 64; ++b) pf[b] = cload(psrc + (b << 8) + tid);
                    ok = true;
#pragma unroll
                    for (int b = 0; b < 64; ++b) ok &= ((pf[b] & 0xFFFFu) == want);
                    if (++it > SPIN) break;
                    __builtin_amdgcn_s_sleep(1);
                }
#pragma unroll
                for (int b = 0; b < 64; ++b) pjk[(b << 8) + tid] = (u16)(pf[b] >> 16);
                if (tid == 0) cstore(fIn, (u32)(t + 2));
            }
            __syncthreads();   // C: pjk staged for next iter
        }
    } else {
        // ====================== X role (feedforward, pipelined) ======================
        const int xid = wg - 8;
        const int s = xid >> 3;                 // 0: X0 (layer0 x), 1: X1 (layer1 x)
        const int g = (xid & 7) >> 1, uh = xid & 1;
        const int l = s;
        const float* Wj = Wjx + (size_t)l * Hn * Hn;
        const float* Wk = Wkx + (size_t)l * Hn * Hn;
        u32* ringOut = (s == 0) ? ringA : ringC;
        const u32* fBP = flags + ((s == 0) ? F_R0(g) : F_R1(g));
        const int ub0 = (uh << 8) + (wave << 6);   // 64 units per wave

        float bj[4], bk[4];
#pragma unroll
        for (int tb = 0; tb < 4; ++tb) {
            const int u = ub0 + (tb << 4) + r15;
            bj[tb] = bjx[l * Hn + u] + bjh[l * Hn + u];
            bk[tb] = bkx[l * Hn + u] + bkh[l * Hn + u];
        }
        __syncthreads();

        for (int t = 0; t < SEQn; ++t) {
            if (t >= RING) {                         // ring back-pressure
                const int bw = t - 7;
                u32 it = 0;
                while ((int)cload(fBP) < bw) {
                    if (++it > SPIN) break;
                    __builtin_amdgcn_s_sleep(1);
                }
            }
            // stage A tile (16 rows x 512) -> aT
            if (s == 0) {
                const float* xs = x + (size_t)t * BH + ((size_t)g << 13);
#pragma unroll
                for (int b = 0; b < 32; ++b) {
                    const int d = (b << 8) + tid, row = d >> 9, col = d & 511;
                    *(u16*)(aT + ((((row << 9) + col) << 1) ^ ((row & 7) << 4))) = f2bf(xs[d]);
                }
            } else {
                const u32* hs = ringB + (size_t)(t & 7) * BH + ((size_t)g << 13);
                u32 v[32]; const u32 want = (u32)(t + 1);
                u32 it = 0;
                while (true) {
                    bool ok = true;
#pragma unroll
                    for (int b = 0; b < 32; ++b) v[b] = cload(hs + (b << 8) + tid);
#pragma unroll
                    for (int b = 0; b < 32; ++b) ok &= ((v[b] & 0xFFFFu) == want);
                    if (__all(ok)) break;
                    if (++it > SPIN) break;
                    __builtin_amdgcn_s_sleep(1);
                }
#pragma unroll
                for (int b = 0; b < 32; ++b) {
                    const int d = (b << 8) + tid, row = d >> 9, col = d & 511;
                    *(u16*)(aT + ((((row << 9) + col) << 1) ^ ((row & 7) << 4))) =
                        (u16)(v[b] >> 16);
                }
            }
            __syncthreads();   // A staged
            if (s == 1 && tid == 0)
                cstore(flags + F_X1((g << 1) | uh), (u32)(t + 1));

            load_afrags();

#pragma unroll
            for (int tb = 0; tb < 4; ++tb) {
                const int uj = ub0 + (tb << 4);
                f32x4 ja = { bj[tb], bj[tb], bj[tb], bj[tb] };
                f32x4 ka = { bk[tb], bk[tb], bk[tb], bk[tb] };
                tile(ja, Wj, uj);
                tile(ka, Wk, uj);
#pragma unroll
                for (int i = 0; i < 4; ++i) {
                    const int row = (q << 2) + i, unit = uj + r15;
                    u32* o = ringOut + (size_t)(t & 7) * NBH +
                             (size_t)(((g << 4) + row) << 10);
                    cstore(o + unit,       ((u32)f2bf(ja[i]) << 16) | (u32)(t + 1));
                    cstore(o + 512 + unit, ((u32)f2bf(ka[i]) << 16) | (u32)(t + 1));
                }
            }
            __syncthreads();   // B: aT frag reads done before next-iter staging
        }
    }
}

extern "C" void kernel_launch(void* const* d_in, const int* in_sizes, int n_in,
                              void* d_out, int out_size, void* d_ws, size_t ws_size,
                              hipStream_t stream) {
    (void)in_sizes; (void)n_in; (void)out_size; (void)ws_size;

    const float* x   = (const float*)d_in[0];
    const float* Wjx = (const float*)d_in[1];
    const float* bjx = (const float*)d_in[2];
    const float* Wjh = (const float*)d_in[3];
    const float* bjh = (const float*)d_in[4];
    const float* Wkx = (const float*)d_in[5];
    const float* bkx = (const float*)d_in[6];
    const float* Wkh = (const float*)d_in[7];
    const float* bkh = (const float*)d_in[8];
    float* out = (float*)d_out;

    char* ws = (char*)d_ws;
    u32* ringA = (u32*)ws;                       // 8*65536*4 = 2 MB
    u32* ringB = (u32*)(ws + 2097152);           // 8*32768*4 = 1 MB
    u32* ringC = (u32*)(ws + 3145728);           // 2 MB
    u32* flags = (u32*)(ws + 5242880);           // 4 KB

    hipMemsetAsync(ws, 0, 5242880 + 4096, stream);

    void* args[] = { (void*)&x, (void*)&Wjx, (void*)&bjx, (void*)&Wjh, (void*)&bjh,
                     (void*)&Wkx, (void*)&bkx, (void*)&Wkh, (void*)&bkh,
                     (void*)&out, (void*)&ringA, (void*)&ringB, (void*)&ringC,
                     (void*)&flags };
    hipError_t err = hipLaunchCooperativeKernel((void*)rnn_pipeline, dim3(24),
                                                dim3(256), args, 0, stream);
    if (err != hipSuccess) {
        // 24 blocks on 256 CUs are trivially co-resident; spins are bounded.
        hipLaunchKernelGGL(rnn_pipeline, dim3(24), dim3(256), 0, stream,
                           x, Wjx, bjx, Wjh, bjh, Wkx, bkx, Wkh, bkh,
                           out, ringA, ringB, ringC, flags);
    }
}

// Round 18
// 2656.078 us; speedup vs baseline: 6.4350x; 6.4350x over previous
//
#include <hip/hip_runtime.h>
#include <hip/hip_bf16.h>

// FF_27650999451977: 2-layer gated RNN (MGU), SEQ=512, B=64, H=IN=512, FP32 I/O.
// FINAL (= round-14, best measured: 2662us, 5.2us/step): weights-stationary
// persistent kernel, stamped-data LLC protocol.
//   - h communicated as (bf16<<16 | step) words: publish/detect/transfer share
//     one LLC round trip; h_prev lives in a register (exact fp32).
//   - L1's two input sweeps overlapped in one poll loop; L0 back-pressure
//     folded into its sweep (33rd load). RING=16 decouples L1 lag.
//   - part[] double-buffered -> 2 barriers/step; all spins bounded;
//     cooperative-launch return checked with plain-launch fallback.
// Structural floor: 512 sequential steps x (cross-CU store-visibility + detect
// through the LLC ~= 5us). XCD-local L2 exchange non-functional (r10-r12, r16);
// row-stationary weight streaming bounded by per-CU L2 BW >= 6.7us/step (r17).

#define SEQn 512
#define Bn   64
#define Hn   512
#define RING 16
#define BH   32768      // Bn*Hn dwords
#define TILE 8192       // 16*512 dwords

#define SPIN_MAIN 262144u

typedef __bf16 bf16x8 __attribute__((ext_vector_type(8)));
typedef float  f32x4  __attribute__((ext_vector_type(4)));
typedef unsigned u32;

__device__ __forceinline__ u32 cload(const u32* p) {
    return __hip_atomic_load(p, __ATOMIC_RELAXED, __HIP_MEMORY_SCOPE_AGENT);
}
__device__ __forceinline__ void cstore(u32* p, u32 v) {
    __hip_atomic_store(p, v, __ATOMIC_RELAXED, __HIP_MEMORY_SCOPE_AGENT);
}
__device__ __forceinline__ unsigned short f2bf(float f) {
    u32 u = __float_as_uint(f);
    u += 0x7FFFu + ((u >> 16) & 1u);   // round-to-nearest-even
    return (unsigned short)(u >> 16);
}
__device__ __forceinline__ bf16x8 cvt8(const float* p) {
    bf16x8 r;
#pragma unroll
    for (int i = 0; i < 8; ++i) r[i] = (__bf16)p[i];
    return r;
}

__global__ void __launch_bounds__(256, 1)
rnn_persistent(const float* __restrict__ x,
               const float* __restrict__ Wjx, const float* __restrict__ bjx,
               const float* __restrict__ Wjh, const float* __restrict__ bjh,
               const float* __restrict__ Wkx, const float* __restrict__ bkx,
               const float* __restrict__ Wkh, const float* __restrict__ bkh,
               float* __restrict__ out,   // [SEQ][B][H] outputs + [2][B][H] hidden
               u32* __restrict__ ring0,   // ws: [RING][B][H] stamped L0 h
               u32* __restrict__ ring1,   // ws: [RING][B][H] stamped L1 h
               u32* __restrict__ flags)   // ws: [4][32] L1 x-consumption progress
{
    const int wg    = blockIdx.x;
    const int layer = wg >> 7;       // 0..1
    const int id    = wg & 127;
    const int mg    = id >> 5;       // 0..3  (16 batch rows each)
    const int ng    = id & 31;       // 0..31 (16 output units each)
    const int tid   = threadIdx.x;
    const int wave  = tid >> 6;      // 0..3  (waves 0,1 = x-side, 2,3 = h-side)
    const int lane  = tid & 63;

    // ---- stationary weights -> bf16 VGPR frags (B-operand: col = lane&15) ----
    const int ucol = ng * 16 + (lane & 15);
    const int koff = (wave & 1) * 256 + ((lane >> 4) << 3);
    const float* wjsrc = ((wave < 2) ? Wjx : Wjh) + (size_t)layer * Hn * Hn + (size_t)ucol * Hn + koff;
    const float* wksrc = ((wave < 2) ? Wkx : Wkh) + (size_t)layer * Hn * Hn + (size_t)ucol * Hn + koff;
    bf16x8 wj[8], wk[8];
#pragma unroll
    for (int kt = 0; kt < 8; ++kt) {
        wj[kt] = cvt8(wjsrc + kt * 32);
        wk[kt] = cvt8(wksrc + kt * 32);
    }

    // ---- epilogue constants: thread tid -> output (row ml, unit nu) ----
    const int ml = tid >> 4;
    const int nu = tid & 15;
    const int ue = ng * 16 + nu;
    const int be = mg * 16 + ml;
    const float bje = bjx[layer * Hn + ue] + bjh[layer * Hn + ue];
    const float bke = bkx[layer * Hn + ue] + bkh[layer * Hn + ue];

    __shared__ float part[2][4][2][16][16];   // 16 KB, double-buffered by t&1
    __shared__ char  xT[16384];
    __shared__ char  hT[16384];

    const int m = mg * 16 + (lane & 15);

    auto compute_global = [&](const float* Abase, int pb) {
        f32x4 aj = {0.f, 0.f, 0.f, 0.f}, ak = {0.f, 0.f, 0.f, 0.f};
        const float* arow = Abase + (size_t)m * Hn + koff;
#pragma unroll
        for (int kt = 0; kt < 8; ++kt) {
            bf16x8 af = cvt8(arow + kt * 32);
            aj = __builtin_amdgcn_mfma_f32_16x16x32_bf16(af, wj[kt], aj, 0, 0, 0);
            ak = __builtin_amdgcn_mfma_f32_16x16x32_bf16(af, wk[kt], ak, 0, 0, 0);
        }
#pragma unroll
        for (int r = 0; r < 4; ++r) {
            part[pb][wave][0][((lane >> 4) << 2) + r][lane & 15] = aj[r];
            part[pb][wave][1][((lane >> 4) << 2) + r][lane & 15] = ak[r];
        }
    };
    auto compute_lds = [&](const char* tile, int pb) {
        f32x4 aj = {0.f, 0.f, 0.f, 0.f}, ak = {0.f, 0.f, 0.f, 0.f};
        const int r       = lane & 15;
        const int cb      = ((wave & 1) << 8) + ((lane >> 4) << 3);
        const int swz     = (r & 7) << 4;
        const int rowbase = r << 10;
#pragma unroll
        for (int kt = 0; kt < 8; ++kt) {
            const int c = cb + kt * 32;
            bf16x8 af = *(const bf16x8*)(tile + ((rowbase + (c << 1)) ^ swz));
            aj = __builtin_amdgcn_mfma_f32_16x16x32_bf16(af, wj[kt], aj, 0, 0, 0);
            ak = __builtin_amdgcn_mfma_f32_16x16x32_bf16(af, wk[kt], ak, 0, 0, 0);
        }
#pragma unroll
        for (int r2 = 0; r2 < 4; ++r2) {
            part[pb][wave][0][((lane >> 4) << 2) + r2][lane & 15] = aj[r2];
            part[pb][wave][1][((lane >> 4) << 2) + r2][lane & 15] = ak[r2];
        }
    };
    auto zero_store = [&](int pb) {
#pragma unroll
        for (int r2 = 0; r2 < 4; ++r2) {
            part[pb][wave][0][((lane >> 4) << 2) + r2][lane & 15] = 0.f;
            part[pb][wave][1][((lane >> 4) << 2) + r2][lane & 15] = 0.f;
        }
    };

    // L0: single-phase sweep-poll with back-pressure folded in (33rd load).
    auto stage_l0 = [&](const u32* src, u32 want, int bwant) {
        u32 v[32];
        const u32* fp = flags + (mg << 5) + (lane & 31);
        u32 it = 0;
        while (true) {
            bool ok = true;
#pragma unroll
            for (int b = 0; b < 32; ++b) v[b] = cload(src + (b << 8) + tid);
            int fv = (int)cload(fp);
#pragma unroll
            for (int b = 0; b < 32; ++b) ok &= ((v[b] & 0xFFFFu) == want);
            ok &= (fv >= bwant);
            if (__all(ok)) break;
            if (++it > SPIN_MAIN) break;      // bounded: fail visibly, never hang
            __builtin_amdgcn_s_sleep(1);
        }
#pragma unroll
        for (int b = 0; b < 32; ++b) {
            const int d = (b << 8) + tid, r = d >> 9;
            *(unsigned short*)(hT + ((d << 1) ^ ((r & 7) << 4))) =
                (unsigned short)(v[b] >> 16);
        }
    };
    // L1: overlapped dual sweep-poll (own-history h + fresh x in one loop).
    auto stage_l1 = [&](const u32* hsrc, const u32* xsrc, u32 hwant, u32 xwant) {
        u32 vh[32], vx[32];
        bool hok = false, xok = false;
        u32 it = 0;
        while (true) {
            if (!hok) {
#pragma unroll
                for (int b = 0; b < 32; ++b) vh[b] = cload(hsrc + (b << 8) + tid);
            }
            if (!xok) {
#pragma unroll
                for (int b = 0; b < 32; ++b) vx[b] = cload(xsrc + (b << 8) + tid);
            }
            bool h2 = true, x2 = true;
#pragma unroll
            for (int b = 0; b < 32; ++b) h2 &= ((vh[b] & 0xFFFFu) == hwant);
#pragma unroll
            for (int b = 0; b < 32; ++b) x2 &= ((vx[b] & 0xFFFFu) == xwant);
            hok = hok || __all(h2);
            xok = xok || __all(x2);
            if (hok && xok) break;
            if (++it > SPIN_MAIN) break;
            __builtin_amdgcn_s_sleep(1);
        }
#pragma unroll
        for (int b = 0; b < 32; ++b) {
            const int d = (b << 8) + tid, r = d >> 9;
            *(unsigned short*)(hT + ((d << 1) ^ ((r & 7) << 4))) =
                (unsigned short)(vh[b] >> 16);
        }
#pragma unroll
        for (int b = 0; b < 32; ++b) {
            const int d = (b << 8) + tid, r = d >> 9;
            *(unsigned short*)(xT + ((d << 1) ^ ((r & 7) << 4))) =
                (unsigned short)(vx[b] >> 16);
        }
    };

    float hprev = 0.f;   // this thread's own h(be,ue) — exact fp32, in register

    for (int t = 0; t < SEQn; ++t) {
        const int pb    = t & 1;
        const int slot  = t & (RING - 1);
        const int pslot = (t - 1) & (RING - 1);
        const u32* hsrc = (layer == 0 ? ring0 : ring1)
                          + (size_t)pslot * BH + mg * TILE;
        const u32* xsrc = ring0 + (size_t)slot * BH + mg * TILE;

        // layer-0 x-side: static input; runs between the previous store and the
        // poll, overlapping the store-visibility window.
        if (layer == 0 && wave < 2)
            compute_global(x + (size_t)t * BH, pb);

        if (layer == 0) {
            if (t > 0) stage_l0(hsrc, (u32)t, t - RING + 1);
            // t==0: no wait; h-side waves will zero_store
        } else {
            stage_l1(hsrc, xsrc, (u32)t, (u32)(t + 1));
        }
        __syncthreads();   // A: tiles staged

        if (layer == 1 && tid == 0)
            cstore(flags + (mg << 5) + ng, (u32)(t + 1));

        if (layer == 0) { if (wave >= 2) { if (t > 0) compute_lds(hT, pb); else zero_store(pb); } }
        else            { if (wave < 2) compute_lds(xT, pb); else compute_lds(hT, pb); }
        __syncthreads();   // B: part[pb] complete

        // ---- epilogue ----
        float sj = part[pb][0][0][ml][nu] + part[pb][1][0][ml][nu] +
                   part[pb][2][0][ml][nu] + part[pb][3][0][ml][nu] + bje;
        float sk = part[pb][0][1][ml][nu] + part[pb][1][1][ml][nu] +
                   part[pb][2][1][ml][nu] + part[pb][3][1][ml][nu] + bke;
        float jj = 1.f / (1.f + __expf(-sj));
        float kk = 1.f / (1.f + __expf(-sk));
        float hnew = jj * (1.f - hprev) + (1.f - kk) * hprev;
        hprev = hnew;

        // self-publishing stamped store (write-through to LLC)
        u32 word = ((u32)f2bf(hnew) << 16) | (u32)(t + 1);
        cstore((layer == 0 ? ring0 : ring1) + (size_t)slot * BH + (size_t)be * Hn + ue, word);

        if (layer == 1)
            out[(size_t)t * BH + (size_t)be * Hn + ue] = hnew;
        if (t == SEQn - 1)
            out[(size_t)SEQn * BH + (size_t)layer * BH + (size_t)be * Hn + ue] = hnew;
        // no barrier C: part[] double-buffered; tile writes happen post-B next iter
    }
}

extern "C" void kernel_launch(void* const* d_in, const int* in_sizes, int n_in,
                              void* d_out, int out_size, void* d_ws, size_t ws_size,
                              hipStream_t stream) {
    (void)in_sizes; (void)n_in; (void)out_size; (void)ws_size;

    const float* x   = (const float*)d_in[0];
    const float* Wjx = (const float*)d_in[1];
    const float* bjx = (const float*)d_in[2];
    const float* Wjh = (const float*)d_in[3];
    const float* bjh = (const float*)d_in[4];
    const float* Wkx = (const float*)d_in[5];
    const float* bkx = (const float*)d_in[6];
    const float* Wkh = (const float*)d_in[7];
    const float* bkh = (const float*)d_in[8];
    float* out = (float*)d_out;

    char* ws = (char*)d_ws;
    u32* ring0 = (u32*)ws;                       // RING*128KB = 2 MB (stamped)
    u32* ring1 = (u32*)(ws + 2097152);           // 2 MB (stamped)
    u32* flags = (u32*)(ws + 4194304);           // 512 B (pad to 4 KB)

    hipMemsetAsync(ws, 0, 4194304 + 4096, stream);

    void* args[] = { (void*)&x, (void*)&Wjx, (void*)&bjx, (void*)&Wjh, (void*)&bjh,
                     (void*)&Wkx, (void*)&bkx, (void*)&Wkh, (void*)&bkh,
                     (void*)&out, (void*)&ring0, (void*)&ring1, (void*)&flags };
    hipError_t err = hipLaunchCooperativeKernel((void*)rnn_persistent, dim3(256),
                                                dim3(256), args, 0, stream);
    if (err != hipSuccess) {
        // 256 blocks at 1 block/CU on 256 CUs are co-resident; spins are bounded.
        hipLaunchKernelGGL(rnn_persistent, dim3(256), dim3(256), 0, stream,
                           x, Wjx, bjx, Wjh, bjh, Wkx, bkx, Wkh, bkh,
                           out, ring0, ring1, flags);
    }
}